// Round 6
// baseline (89.777 us; speedup 1.0000x reference)
//
#include <hip/hip_runtime.h>
#include <cstdint>

typedef unsigned long long u64;
typedef unsigned int u32;
typedef unsigned char u8;

#define DIM     10000
#define NCLS    100
#define BATCH   4096
#define F4ROW   2500        // float4s per input row (10000/4)
#define ROWB    2560        // padded bytes per packed row
#define W64     320         // u64 words per packed row
#define NCG     25          // classes per wave (blockIdx.y: 4 groups)
#define ZS      8           // k-split (blockIdx.z)
#define WZ      (W64 / ZS)  // 40 u64 words per z-slice
#define OUTN    (BATCH * NCLS)

// Nibble packing (UNCHANGED from round 5): float4 #i of a row -> byte i,
// bits 0..3 = (v.{x,y,z,w} > 0.5). Pad bytes are 0 in BOTH q and am.

// one block (4 waves) per row; wave wq covers f4 indices [wq*640, wq*640+640)
__global__ __launch_bounds__(256) void pack_kernel(const float* __restrict__ in,
                                                   u8* __restrict__ outp) {
    const int lane = threadIdx.x & 63;
    const int wq   = threadIdx.x >> 6;
    const int r    = blockIdx.x;
    const float* row = in + (size_t)r * DIM;
    u8* orow = outp + (size_t)r * ROWB;
#pragma unroll
    for (int u = 0; u < 10; ++u) {
        const int idx = wq * 640 + u * 64 + lane;       // byte / f4 index
        float4 v = make_float4(0.f, 0.f, 0.f, 0.f);
        if (idx < F4ROW) v = *(const float4*)(row + (size_t)idx * 4);
        const u8 b = (u8)((v.x > 0.5f ? 1u : 0u) | (v.y > 0.5f ? 2u : 0u) |
                          (v.z > 0.5f ? 4u : 0u) | (v.w > 0.5f ? 8u : 0u));
        orow[idx] = b;                                   // 64 B contiguous per wave
    }
}

// 1 wave per block. lane = query row. c0, z from blockIdx only -> ap addresses
// provably uniform -> scalar loads (s_load), off the VMEM pipe. 25 classes per
// wave amortize each q load over 100 MACs. grid (64, 4, 8), block 64.
__global__ __launch_bounds__(64) void hamming2(const u64* __restrict__ qp,
                                               const u64* __restrict__ ap,
                                               int* __restrict__ partial) {
    const int lane = threadIdx.x;
    const int r    = blockIdx.x * 64 + lane;
    const int c0   = blockIdx.y * NCG;
    const int z    = blockIdx.z;
    const u64* qrow = qp + (size_t)r * W64 + (size_t)z * WZ;   // per-lane stream
    const u64* ab   = ap + (size_t)z * WZ;

    int acc[NCG];
#pragma unroll
    for (int j = 0; j < NCG; ++j) acc[j] = 0;

    for (int k = 0; k < WZ; k += 4) {                    // 10 steps of 4 u64
        const ulonglong2 q01 = *(const ulonglong2*)(qrow + k);
        const ulonglong2 q23 = *(const ulonglong2*)(qrow + k + 2);
#pragma unroll
        for (int j = 0; j < NCG; ++j) {
            const u64* arow = ab + (size_t)(c0 + j) * W64 + k;  // uniform
            const ulonglong2 a01 = *(const ulonglong2*)(arow);
            const ulonglong2 a23 = *(const ulonglong2*)(arow + 2);
            acc[j] += __popcll(q01.x ^ a01.x) + __popcll(q01.y ^ a01.y)
                    + __popcll(q23.x ^ a23.x) + __popcll(q23.y ^ a23.y);
        }
    }
    int* pout = partial + (size_t)z * OUTN + (size_t)r * NCLS + c0;
#pragma unroll
    for (int j = 0; j < NCG; ++j) pout[j] = acc[j];      // L2-merged lines
}

// out = DIM - sum_z partial[z]; fully coalesced both sides.
__global__ __launch_bounds__(256) void combine2(const int* __restrict__ partial,
                                                float* __restrict__ out) {
    const int i = blockIdx.x * 256 + threadIdx.x;
    int s = 0;
#pragma unroll
    for (int z = 0; z < ZS; ++z) s += partial[(size_t)z * OUTN + i];
    out[i] = (float)(DIM - s);
}

extern "C" void kernel_launch(void* const* d_in, const int* in_sizes, int n_in,
                              void* d_out, int out_size, void* d_ws, size_t ws_size,
                              hipStream_t stream) {
    const float* q = (const float*)d_in[0];   // [4096, 10000] f32 {0,1}
    const float* a = (const float*)d_in[1];   // [100, 10000]  f32 {0,1}
    float* out = (float*)d_out;               // [4096, 100]   f32

    // ws layout (16B-aligned):
    //   ap:      offset 0        (100*2560  = 256,000 B)
    //   qp:      offset 512 KiB  (4096*2560 = 10,485,760 B)
    //   partial: offset 16 MiB   (8*409600*4 = 13,107,200 B)
    u8*  ap8  = (u8*)d_ws;
    u8*  qp8  = (u8*)d_ws + (512u << 10);
    int* part = (int*)((char*)d_ws + (16u << 20));

    pack_kernel<<<NCLS,  256, 0, stream>>>(a, ap8);
    pack_kernel<<<BATCH, 256, 0, stream>>>(q, qp8);
    hamming2<<<dim3(BATCH / 64, NCLS / NCG, ZS), 64, 0, stream>>>(
        (const u64*)qp8, (const u64*)ap8, part);
    combine2<<<OUTN / 256, 256, 0, stream>>>(part, out);
}

// Round 7
// 83.085 us; speedup vs baseline: 1.0805x; 1.0805x over previous
//
#include <hip/hip_runtime.h>
#include <cstdint>

typedef unsigned long long u64;
typedef unsigned int u32;

#define DIM    10000
#define NCLS   100
#define BATCH  4096
#define ZQ     4                 // z-quarters of the dim axis
#define WPZ    20                // ulonglong2 word-pairs per z (80 total = 160 u64)
#define CHZ    10                // 256-dim chunks per z (40 total)
#define RPB    8                 // query rows per fused block
#define OUTN   (BATCH * NCLS)
#define APL_N  (WPZ * NCLS)      // 2000 ulonglong2 = 32000 B
#define LDSB   (APL_N * 16 + RPB * 2 * CHZ * 16)   // 32000 + 2560 = 34560 B

// Bit order (identical for q and am): chunk C covers dims [C*256, C*256+256);
// word w = 4C+j, bit i <- dim C*256 + 4i + j (ballot lane i, float4 elem j).
// wpair = w>>1; z = wpair/WPZ. Pad dims (>= DIM) give 0-bits on BOTH sides.

// ---- pack am -> apT2 global, layout [80 wpairs][100 classes] ulonglong2 ----
// one wave per class row; grid 25 x 256 (exactly 100 waves)
__global__ __launch_bounds__(256) void pack_a_t(const float* __restrict__ a,
                                                ulonglong2* __restrict__ apT2) {
    const int lane = threadIdx.x & 63;
    const int r    = blockIdx.x * 4 + (threadIdx.x >> 6);   // class 0..99
    const float* row = a + (size_t)r * DIM;
    for (int C = 0; C < 40; ++C) {
        const int d0 = C * 256 + lane * 4;
        float4 v = make_float4(0.f, 0.f, 0.f, 0.f);
        if (d0 < DIM) v = *(const float4*)(row + d0);
        const u64 b0 = __ballot(v.x > 0.5f);
        const u64 b1 = __ballot(v.y > 0.5f);
        const u64 b2 = __ballot(v.z > 0.5f);
        const u64 b3 = __ballot(v.w > 0.5f);
        if (lane < 2) {
            ulonglong2 u;
            u.x = lane ? b2 : b0;
            u.y = lane ? b3 : b1;
            apT2[(size_t)(2 * C + lane) * NCLS + r] = u;    // wpair = 2C+lane
        }
    }
}

// ---- fused: read q (once), pack to LDS via ballot, hamming vs LDS-resident ap
// grid (BATCH/RPB, ZQ), block 512 (8 waves; wave = one query row)
__global__ __launch_bounds__(512) void fused(const float* __restrict__ q,
                                             const ulonglong2* __restrict__ apT2,
                                             int* __restrict__ partial) {
    extern __shared__ char smem[];
    ulonglong2* apL = (ulonglong2*)smem;                    // [WPZ][NCLS]
    ulonglong2* qb  = (ulonglong2*)(smem + APL_N * 16);     // [RPB][2*CHZ]
    const int tid  = threadIdx.x;
    const int lane = tid & 63;
    const int wv   = tid >> 6;                              // 0..7 = local row
    const int z    = blockIdx.y;
    const int r    = blockIdx.x * RPB + wv;

    // (i) ap z-slice -> LDS, straight linear copy (32 KB from L2)
    for (int i = tid; i < APL_N; i += 512)
        apL[i] = apT2[(size_t)z * APL_N + i];

    // (ii) pack this wave's row-quarter into qb (ballot; q never re-written)
    const float* row = q + (size_t)r * DIM;
#pragma unroll
    for (int lc = 0; lc < CHZ; ++lc) {
        const int d0 = (z * CHZ + lc) * 256 + lane * 4;
        float4 v = make_float4(0.f, 0.f, 0.f, 0.f);
        if (d0 < DIM) v = *(const float4*)(row + d0);       // 1 KB/wave coalesced
        const u64 b0 = __ballot(v.x > 0.5f);
        const u64 b1 = __ballot(v.y > 0.5f);
        const u64 b2 = __ballot(v.z > 0.5f);
        const u64 b3 = __ballot(v.w > 0.5f);
        if (lane < 2) {
            ulonglong2 u;
            u.x = lane ? b2 : b0;
            u.y = lane ? b3 : b1;
            qb[wv * (2 * CHZ) + 2 * lc + lane] = u;
        }
    }
    __syncthreads();

    // (iii) hamming: lane = class (pass A: lane, pass B: 64+lane for lane<36)
    const ulonglong2* qrow = qb + wv * (2 * CHZ);
    int acc0 = 0, acc1 = 0;
#pragma unroll
    for (int wp = 0; wp < WPZ; ++wp) {
        const ulonglong2 qv = qrow[wp];                     // LDS broadcast
        const ulonglong2 a0 = apL[wp * NCLS + lane];        // b128, 2-way free
        acc0 += __popcll(qv.x ^ a0.x) + __popcll(qv.y ^ a0.y);
        if (lane < NCLS - 64) {
            const ulonglong2 a1 = apL[wp * NCLS + 64 + lane];
            acc1 += __popcll(qv.x ^ a1.x) + __popcll(qv.y ^ a1.y);
        }
    }
    int* p = partial + (size_t)z * OUTN + (size_t)r * NCLS;
    p[lane] = acc0;                                         // coalesced
    if (lane < NCLS - 64) p[64 + lane] = acc1;
}

// ---- combine: out = DIM - sum_z partial[z] (exact ints -> exact float) ----
__global__ __launch_bounds__(256) void combine(const int* __restrict__ partial,
                                               float* __restrict__ out) {
    const int i = blockIdx.x * 256 + threadIdx.x;
    int s = 0;
#pragma unroll
    for (int zz = 0; zz < ZQ; ++zz) s += partial[(size_t)zz * OUTN + i];
    out[i] = (float)(DIM - s);
}

extern "C" void kernel_launch(void* const* d_in, const int* in_sizes, int n_in,
                              void* d_out, int out_size, void* d_ws, size_t ws_size,
                              hipStream_t stream) {
    const float* q = (const float*)d_in[0];   // [4096, 10000] f32 {0,1}
    const float* a = (const float*)d_in[1];   // [100, 10000]  f32 {0,1}
    float* out = (float*)d_out;               // [4096, 100]   f32

    // ws: apT2 (80*100*16 = 128,000 B) at 0; partial (4*409600*4 B) at 1 MiB
    ulonglong2* apT2 = (ulonglong2*)d_ws;
    int*        part = (int*)((char*)d_ws + (1u << 20));

    pack_a_t<<<25, 256, 0, stream>>>(a, apT2);
    fused<<<dim3(BATCH / RPB, ZQ), 512, LDSB, stream>>>(q, apT2, part);
    combine<<<OUTN / 256, 256, 0, stream>>>(part, out);
}

// Round 8
// 74.576 us; speedup vs baseline: 1.2038x; 1.1141x over previous
//
#include <hip/hip_runtime.h>
#include <cstdint>

typedef unsigned long long u64;
typedef unsigned int u32;
typedef unsigned char u8;

#define DIM     10000
#define NCLS    100
#define BATCH   4096
#define F4ROW   2500        // float4s per input row
#define ROWB    2560        // padded bytes per packed row
#define W64     320         // u64 words per packed row
#define NC      10          // classes per hamming block
#define ZSPLIT  4           // word-range split
#define WZ      (W64 / ZSPLIT)   // 80 u64 per z-slice
#define OUTN    (BATCH * NCLS)   // 409600

// Nibble packing (layout identical to round 5): float4 #c of row r -> byte
// qp[r*2560 + c], bits 0..3 = (v.{x,y,z,w} > 0.5). Pad bytes (col >= 2500)
// are 0 in BOTH q and am -> XOR contributes nothing.

// ---- pure-streaming pack: grid-stride over the padded byte domain ----
// Each iteration: one unconditional-ish float4 load + one byte store.
// row = b/2560 via exact magic ( (b>>9) * 52429 >> 18, valid for b>>9 < 81919 ).
__global__ __launch_bounds__(256) void pack_stream(const float* __restrict__ in,
                                                   u8* __restrict__ outp,
                                                   const int nbytes) {
    const int stride = gridDim.x * 256;
    int b = blockIdx.x * 256 + threadIdx.x;
#pragma unroll 4
    for (; b < nbytes; b += stride) {
        const u32 row = ((u32)(b >> 9) * 52429u) >> 18;   // b / 2560
        const u32 col = (u32)b - row * 2560u;             // byte in row
        u8 v8 = 0;
        if (col < F4ROW) {
            const float4 v = *(const float4*)(in + ((size_t)row * F4ROW + col) * 4);
            v8 = (u8)((v.x > 0.5f ? 1u : 0u) | (v.y > 0.5f ? 2u : 0u) |
                      (v.z > 0.5f ? 4u : 0u) | (v.w > 0.5f ? 8u : 0u));
        }
        outp[b] = v8;
    }
}

// ---- hamming (VERBATIM round 5 — experiment control) ----
// lane = one query row; each block: 256 rows x NC classes x 1/ZSPLIT of words.
__global__ __launch_bounds__(256) void hamming_kernel(const u64* __restrict__ qp,
                                                      const u64* __restrict__ ap,
                                                      int* __restrict__ partial) {
    const int r  = blockIdx.x * 256 + threadIdx.x;
    const int c0 = blockIdx.y * NC;
    const int z  = blockIdx.z;
    const u64* qrow  = qp + (size_t)r * W64 + (size_t)z * WZ;
    const u64* abase = ap + (size_t)z * WZ;

    int acc[NC];
#pragma unroll
    for (int j = 0; j < NC; ++j) acc[j] = 0;

    for (int wt = 0; wt < WZ; wt += 8) {                // 10 tiles of 8 u64
        ulonglong2 qv[4];
#pragma unroll
        for (int k = 0; k < 4; ++k)
            qv[k] = *(const ulonglong2*)(qrow + wt + 2 * k);  // 16 B/lane
#pragma unroll
        for (int j = 0; j < NC; ++j) {
            const u64* aw = abase + (size_t)(c0 + j) * W64 + wt;  // wave-uniform
            int s = 0;
#pragma unroll
            for (int k = 0; k < 4; ++k) {
                s += __popcll(qv[k].x ^ aw[2 * k]);
                s += __popcll(qv[k].y ^ aw[2 * k + 1]);
            }
            acc[j] += s;
        }
    }
    int* pout = partial + (size_t)z * OUTN + (size_t)r * NCLS + c0;
#pragma unroll
    for (int j = 0; j < NC; ++j) pout[j] = acc[j];
}

// ---- combine (VERBATIM round 5) ----
__global__ __launch_bounds__(256) void combine_kernel(const int* __restrict__ partial,
                                                      float* __restrict__ out) {
    const int i = blockIdx.x * 256 + threadIdx.x;
    const int s = partial[i] + partial[i + OUTN] + partial[i + 2 * OUTN] +
                  partial[i + 3 * OUTN];
    out[i] = (float)(DIM - s);
}

extern "C" void kernel_launch(void* const* d_in, const int* in_sizes, int n_in,
                              void* d_out, int out_size, void* d_ws, size_t ws_size,
                              hipStream_t stream) {
    const float* q = (const float*)d_in[0];   // [4096, 10000] f32 {0,1}
    const float* a = (const float*)d_in[1];   // [100, 10000]  f32 {0,1}
    float* out = (float*)d_out;               // [4096, 100]   f32

    // ws layout (16B-aligned):
    //   ap:      offset 0        (100*2560  = 256,000 B)
    //   qp:      offset 512 KiB  (4096*2560 = 10,485,760 B)
    //   partial: offset 12 MiB   (4*409600*4 = 6,553,600 B)
    u8*  ap8  = (u8*)d_ws;
    u8*  qp8  = (u8*)d_ws + (512u << 10);
    int* part = (int*)((char*)d_ws + (12u << 20));

    pack_stream<<<256,  256, 0, stream>>>(a, ap8, NCLS * ROWB);
    pack_stream<<<2048, 256, 0, stream>>>(q, qp8, BATCH * ROWB);
    hamming_kernel<<<dim3(BATCH / 256, NCLS / NC, ZSPLIT), 256, 0, stream>>>(
        (const u64*)qp8, (const u64*)ap8, part);
    combine_kernel<<<OUTN / 256, 256, 0, stream>>>(part, out);
}

// Round 9
// 74.395 us; speedup vs baseline: 1.2068x; 1.0024x over previous
//
#include <hip/hip_runtime.h>
#include <cstdint>

typedef unsigned long long u64;
typedef unsigned int u32;
typedef unsigned char u8;

#define DIM     10000
#define NCLS    100
#define BATCH   4096
#define F4ROW   2500        // float4s per input row
#define ROWB    2560        // padded bytes per packed row
#define W64     320         // u64 words per packed row
#define NC      10          // classes per hamming block
#define ZSPLIT  4           // word-range split
#define WZ      (W64 / ZSPLIT)   // 80 u64 per z-slice
#define OUTN    (BATCH * NCLS)   // 409600

// Nibble packing (layout identical to rounds 5/8): float4 #c of row r -> byte
// qp[r*2560 + c], bits 0..3 = (v.{x,y,z,w} > 0.5). Pad bytes (col >= 2500)
// are 0 in BOTH q and am -> XOR contributes nothing.

// ---- pack v2: per-row block, UNCONDITIONAL clamped loads (hoistable) ----
// block = one row (4 waves); wave wq handles byte indices wq*640 .. wq*640+639.
// No branch anywhere in the body: the load address is clamped in-bounds and
// the value is selected to 0 for pad bytes. 10 independent loads in flight.
__global__ __launch_bounds__(256) void pack_kernel2(const float* __restrict__ in,
                                                    u8* __restrict__ outp) {
    const int lane = threadIdx.x & 63;
    const int wq   = threadIdx.x >> 6;
    const int r    = blockIdx.x;
    const float* row = in + (size_t)r * DIM;
    u8* orow = outp + (size_t)r * ROWB;
#pragma unroll
    for (int u = 0; u < 10; ++u) {
        const int idx  = wq * 640 + u * 64 + lane;        // 0..2559
        const int lidx = idx < F4ROW ? idx : F4ROW - 1;   // clamp: always valid
        const float4 v = *(const float4*)(row + (size_t)lidx * 4);  // unconditional
        u8 b = (u8)((v.x > 0.5f ? 1u : 0u) | (v.y > 0.5f ? 2u : 0u) |
                    (v.z > 0.5f ? 4u : 0u) | (v.w > 0.5f ? 8u : 0u));
        b = (idx < F4ROW) ? b : (u8)0;                    // value-select, no branch
        orow[idx] = b;                                    // unconditional store
    }
}

// ---- hamming (VERBATIM rounds 5/8 — experiment control) ----
__global__ __launch_bounds__(256) void hamming_kernel(const u64* __restrict__ qp,
                                                      const u64* __restrict__ ap,
                                                      int* __restrict__ partial) {
    const int r  = blockIdx.x * 256 + threadIdx.x;
    const int c0 = blockIdx.y * NC;
    const int z  = blockIdx.z;
    const u64* qrow  = qp + (size_t)r * W64 + (size_t)z * WZ;
    const u64* abase = ap + (size_t)z * WZ;

    int acc[NC];
#pragma unroll
    for (int j = 0; j < NC; ++j) acc[j] = 0;

    for (int wt = 0; wt < WZ; wt += 8) {                // 10 tiles of 8 u64
        ulonglong2 qv[4];
#pragma unroll
        for (int k = 0; k < 4; ++k)
            qv[k] = *(const ulonglong2*)(qrow + wt + 2 * k);  // 16 B/lane
#pragma unroll
        for (int j = 0; j < NC; ++j) {
            const u64* aw = abase + (size_t)(c0 + j) * W64 + wt;  // wave-uniform
            int s = 0;
#pragma unroll
            for (int k = 0; k < 4; ++k) {
                s += __popcll(qv[k].x ^ aw[2 * k]);
                s += __popcll(qv[k].y ^ aw[2 * k + 1]);
            }
            acc[j] += s;
        }
    }
    int* pout = partial + (size_t)z * OUTN + (size_t)r * NCLS + c0;
#pragma unroll
    for (int j = 0; j < NC; ++j) pout[j] = acc[j];
}

// ---- combine (VERBATIM rounds 5/8) ----
__global__ __launch_bounds__(256) void combine_kernel(const int* __restrict__ partial,
                                                      float* __restrict__ out) {
    const int i = blockIdx.x * 256 + threadIdx.x;
    const int s = partial[i] + partial[i + OUTN] + partial[i + 2 * OUTN] +
                  partial[i + 3 * OUTN];
    out[i] = (float)(DIM - s);
}

extern "C" void kernel_launch(void* const* d_in, const int* in_sizes, int n_in,
                              void* d_out, int out_size, void* d_ws, size_t ws_size,
                              hipStream_t stream) {
    const float* q = (const float*)d_in[0];   // [4096, 10000] f32 {0,1}
    const float* a = (const float*)d_in[1];   // [100, 10000]  f32 {0,1}
    float* out = (float*)d_out;               // [4096, 100]   f32

    // ws layout (16B-aligned):
    //   ap:      offset 0        (100*2560  = 256,000 B)
    //   qp:      offset 512 KiB  (4096*2560 = 10,485,760 B)
    //   partial: offset 12 MiB   (4*409600*4 = 6,553,600 B)
    u8*  ap8  = (u8*)d_ws;
    u8*  qp8  = (u8*)d_ws + (512u << 10);
    int* part = (int*)((char*)d_ws + (12u << 20));

    pack_kernel2<<<NCLS,  256, 0, stream>>>(a, ap8);
    pack_kernel2<<<BATCH, 256, 0, stream>>>(q, qp8);
    hamming_kernel<<<dim3(BATCH / 256, NCLS / NC, ZSPLIT), 256, 0, stream>>>(
        (const u64*)qp8, (const u64*)ap8, part);
    combine_kernel<<<OUTN / 256, 256, 0, stream>>>(part, out);
}

// Round 10
// 50.578 us; speedup vs baseline: 1.7750x; 1.4709x over previous
//
#include <hip/hip_runtime.h>
#include <cstdint>

typedef unsigned long long u64;
typedef unsigned int u32;

#define DIM    10000
#define NCLS   100
#define BATCH  4096
#define F4ROW  2500          // float4s per input row
#define NCH    40            // 256-dim chunks per row (chunk 39 partial)

// Bit order (identical for q and am): chunk C covers dims [C*256, C*256+256);
// word j of chunk C, bit i <- dim C*256 + 4i + j (ballot lane i, float4 elem j).
// apT2 layout: [wpair = 2C + (j>>1)][class], .x = word j=0/2, .y = word j=1/3.
// Pad dims (>= DIM) give 0-bits on BOTH operands -> XOR contributes nothing.

// ---- pack am -> apT2 (VERBATIM round 7, known-correct) ----
// one wave per class row; grid 25 x 256 (exactly 100 waves)
__global__ __launch_bounds__(256) void pack_a_t(const float* __restrict__ a,
                                                ulonglong2* __restrict__ apT2) {
    const int lane = threadIdx.x & 63;
    const int r    = blockIdx.x * 4 + (threadIdx.x >> 6);   // class 0..99
    const float* row = a + (size_t)r * DIM;
    for (int C = 0; C < NCH; ++C) {
        const int d0 = C * 256 + lane * 4;
        float4 v = make_float4(0.f, 0.f, 0.f, 0.f);
        if (d0 < DIM) v = *(const float4*)(row + d0);
        const u64 b0 = __ballot(v.x > 0.5f);
        const u64 b1 = __ballot(v.y > 0.5f);
        const u64 b2 = __ballot(v.z > 0.5f);
        const u64 b3 = __ballot(v.w > 0.5f);
        if (lane < 2) {
            ulonglong2 u;
            u.x = lane ? b2 : b0;
            u.y = lane ? b3 : b1;
            apT2[(size_t)(2 * C + lane) * NCLS + r] = u;    // wpair = 2C+lane
        }
    }
}

// ---- fused: q -> ballot (wave-uniform SGPR words) -> hamming -> out ----
// wave = one query row; lane L owns class L and class 64+min(L,35).
// No LDS, no syncthreads, no intermediate global traffic.
// grid BATCH/4 x 256 (4 waves/block) = 4096 waves = 16 waves/CU.
__global__ __launch_bounds__(256) void fused_v2(const float* __restrict__ q,
                                                const ulonglong2* __restrict__ apT2,
                                                float* __restrict__ out) {
    const int lane = threadIdx.x & 63;
    const int r    = blockIdx.x * 4 + (threadIdx.x >> 6);   // query row
    const float* row = q + (size_t)r * DIM;

    const int clsA = lane;                                  // 0..63
    const int clsB = 64 + (lane < NCLS - 64 ? lane : NCLS - 65);  // 64..99 (clamped)
    u32 accA = 0, accB = 0;

#pragma unroll 4
    for (int C = 0; C < NCH; ++C) {
        const int idx  = C * 64 + lane;                     // float4 index
        const int lidx = idx < F4ROW ? idx : F4ROW - 1;     // clamp: always valid
        const float4 v = *(const float4*)(row + (size_t)lidx * 4);  // 1 KB/wave
        const bool ok  = (idx < F4ROW);
        const u64 b0 = __ballot(ok && (v.x > 0.5f));        // wave-uniform words
        const u64 b1 = __ballot(ok && (v.y > 0.5f));
        const u64 b2 = __ballot(ok && (v.z > 0.5f));
        const u64 b3 = __ballot(ok && (v.w > 0.5f));

        const ulonglong2* wp0 = apT2 + (size_t)(2 * C) * NCLS;
        const ulonglong2* wp1 = wp0 + NCLS;
        const ulonglong2 aA0 = wp0[clsA];                   // coalesced 16 B/lane
        const ulonglong2 aA1 = wp1[clsA];
        const ulonglong2 aB0 = wp0[clsB];
        const ulonglong2 aB1 = wp1[clsB];

        accA += (u32)(__popcll(b0 ^ aA0.x) + __popcll(b1 ^ aA0.y) +
                      __popcll(b2 ^ aA1.x) + __popcll(b3 ^ aA1.y));
        accB += (u32)(__popcll(b0 ^ aB0.x) + __popcll(b1 ^ aB0.y) +
                      __popcll(b2 ^ aB1.x) + __popcll(b3 ^ aB1.y));
    }

    float* orow = out + (size_t)r * NCLS;
    orow[clsA] = (float)(DIM - (int)accA);                  // coalesced
    if (lane < NCLS - 64) orow[64 + lane] = (float)(DIM - (int)accB);
}

extern "C" void kernel_launch(void* const* d_in, const int* in_sizes, int n_in,
                              void* d_out, int out_size, void* d_ws, size_t ws_size,
                              hipStream_t stream) {
    const float* q = (const float*)d_in[0];   // [4096, 10000] f32 {0,1}
    const float* a = (const float*)d_in[1];   // [100, 10000]  f32 {0,1}
    float* out = (float*)d_out;               // [4096, 100]   f32

    // ws: apT2 only (80 wpairs * 100 classes * 16 B = 128,000 B)
    ulonglong2* apT2 = (ulonglong2*)d_ws;

    pack_a_t<<<25, 256, 0, stream>>>(a, apT2);
    fused_v2<<<BATCH / 4, 256, 0, stream>>>(q, apT2, out);
}